// Round 6
// baseline (98.110 us; speedup 1.0000x reference)
//
#include <hip/hip_runtime.h>

#define D 128
#define EPS 1e-3f
#define THREADS 512
#define ROWS_PER_BLOCK 32   // 8 waves * 4 rows
#define N_BLOCKS 256        // 8192 rows total

__device__ __forceinline__ float softplus_f(float x) {
    return (x > 20.f) ? x : log1pf(expf(x));
}

__global__ __launch_bounds__(THREADS, 1)
void lu_flow_kernel(const float* __restrict__ x,
                    const int*   __restrict__ mask,
                    const float* __restrict__ low_e,
                    const float* __restrict__ up_e,
                    const float* __restrict__ ud,
                    const float* __restrict__ bias,
                    float* __restrict__ out_y,
                    float* __restrict__ out_logdet,
                    float* __restrict__ out_mask)
{
    // UT[j*D+i] = U[i][j], LT[j*D+i] = L[i][j]  (transposed: matvec reads are
    // contiguous across lanes -> conflict-free)
    __shared__ float UT[D * D];
    __shared__ float LT[D * D];
    __shared__ float stage[8][4 * D];   // per-wave xm then tm for 4 rows

    const int tid  = threadIdx.x;
    const int lane = tid & 63;
    const int w    = tid >> 6;

    // ---- build U^T, L^T in LDS (i fast-varying -> conflict-free LDS writes) ----
    for (int p = tid; p < D * D; p += THREADS) {
        const int i = p & (D - 1);
        const int j = p >> 7;
        float uv, lv;
        if (j > i) {
            // triu_indices(D,1) row-major: idx = i*127 - i(i-1)/2 + (j-i-1)
            uv = up_e[i * 127 - (i * (i - 1)) / 2 + (j - i - 1)];
            lv = 0.f;
        } else if (j < i) {
            // tril_indices(D,-1) row-major: idx = i(i-1)/2 + j
            uv = 0.f;
            lv = low_e[(i * (i - 1)) / 2 + j];
        } else {
            uv = softplus_f(ud[i]) + EPS;
            lv = 1.f;
        }
        UT[p] = uv;   // p = j*D + i
        LT[p] = lv;
    }

    // ---- per-lane constants (own output positions i0,i1) ----
    const int i0 = 2 * lane, i1 = 2 * lane + 1;
    const float logd0 = logf(softplus_f(ud[i0]) + EPS);
    const float logd1 = logf(softplus_f(ud[i1]) + EPS);
    const float b0 = bias[i0], b1 = bias[i1];

    const int row_base = blockIdx.x * ROWS_PER_BLOCK + w * 4;

    float xs[4][2];
    int   ms[4][2];

    #pragma unroll
    for (int r = 0; r < 4; ++r) {
        const int row = row_base + r;
        const float* xr = x    + (size_t)row * D;
        const int*   mr = mask + (size_t)row * D;
        float2 xv = *(const float2*)(xr + i0);
        int2   mv = *(const int2*)(mr + i0);
        xs[r][0] = xv.x; xs[r][1] = xv.y;
        ms[r][0] = mv.x; ms[r][1] = mv.y;

        float2 xmv;
        xmv.x = mv.x ? xv.x : 0.f;
        xmv.y = mv.y ? xv.y : 0.f;
        *(float2*)&stage[w][r * D + i0] = xmv;

        // mask passthrough (output 2), as float 0/1
        float2 mf; mf.x = (float)mv.x; mf.y = (float)mv.y;
        *(float2*)(out_mask + (size_t)row * D + i0) = mf;

        // log_det = sum_i m_i * log(diag_i)  (wave butterfly reduce)
        float part = (mv.x ? logd0 : 0.f) + (mv.y ? logd1 : 0.f);
        #pragma unroll
        for (int s = 32; s > 0; s >>= 1) part += __shfl_xor(part, s, 64);
        if (lane == 0) out_logdet[row] = part;
    }

    __syncthreads();

    // ---- matvec A: t = U * xm   (t[i] = sum_j UT[j*D+i] * xm[j]) ----
    float accA[4][2] = {{0.f,0.f},{0.f,0.f},{0.f,0.f},{0.f,0.f}};
    for (int j4 = 0; j4 < D; j4 += 4) {
        float4 xr4[4];
        #pragma unroll
        for (int r = 0; r < 4; ++r)
            xr4[r] = *(const float4*)&stage[w][r * D + j4];   // uniform addr: broadcast
        #pragma unroll
        for (int jj = 0; jj < 4; ++jj) {
            float2 u = *(const float2*)&UT[(j4 + jj) * D + i0];
            #pragma unroll
            for (int r = 0; r < 4; ++r) {
                const float xv = (jj == 0) ? xr4[r].x : (jj == 1) ? xr4[r].y
                               : (jj == 2) ? xr4[r].z : xr4[r].w;
                accA[r][0] = fmaf(u.x, xv, accA[r][0]);
                accA[r][1] = fmaf(u.y, xv, accA[r][1]);
            }
        }
    }

    __syncthreads();

    // ---- tm = m .* t  back into stage ----
    #pragma unroll
    for (int r = 0; r < 4; ++r) {
        float2 tmv;
        tmv.x = ms[r][0] ? accA[r][0] : 0.f;
        tmv.y = ms[r][1] ? accA[r][1] : 0.f;
        *(float2*)&stage[w][r * D + i0] = tmv;
    }

    __syncthreads();

    // ---- matvec B: s = L * tm ----
    float accB[4][2] = {{0.f,0.f},{0.f,0.f},{0.f,0.f},{0.f,0.f}};
    for (int j4 = 0; j4 < D; j4 += 4) {
        float4 xr4[4];
        #pragma unroll
        for (int r = 0; r < 4; ++r)
            xr4[r] = *(const float4*)&stage[w][r * D + j4];
        #pragma unroll
        for (int jj = 0; jj < 4; ++jj) {
            float2 u = *(const float2*)&LT[(j4 + jj) * D + i0];
            #pragma unroll
            for (int r = 0; r < 4; ++r) {
                const float xv = (jj == 0) ? xr4[r].x : (jj == 1) ? xr4[r].y
                               : (jj == 2) ? xr4[r].z : xr4[r].w;
                accB[r][0] = fmaf(u.x, xv, accB[r][0]);
                accB[r][1] = fmaf(u.y, xv, accB[r][1]);
            }
        }
    }

    // ---- final: y = m ? (s + bias) : x ----
    #pragma unroll
    for (int r = 0; r < 4; ++r) {
        const int row = row_base + r;
        float2 yv;
        yv.x = ms[r][0] ? (accB[r][0] + b0) : xs[r][0];
        yv.y = ms[r][1] ? (accB[r][1] + b1) : xs[r][1];
        *(float2*)(out_y + (size_t)row * D + i0) = yv;
    }
}

extern "C" void kernel_launch(void* const* d_in, const int* in_sizes, int n_in,
                              void* d_out, int out_size, void* d_ws, size_t ws_size,
                              hipStream_t stream) {
    const float* x     = (const float*)d_in[0];
    const int*   mask  = (const int*)d_in[1];
    const float* low_e = (const float*)d_in[2];
    const float* up_e  = (const float*)d_in[3];
    const float* ud    = (const float*)d_in[4];
    const float* bias  = (const float*)d_in[5];

    const int n_rows = in_sizes[0] / D;            // 8192
    float* out_y      = (float*)d_out;             // n_rows*D
    float* out_logdet = out_y + (size_t)n_rows * D;
    float* out_mask   = out_logdet + n_rows;       // n_rows*D, as float 0/1

    lu_flow_kernel<<<N_BLOCKS, THREADS, 0, stream>>>(
        x, mask, low_e, up_e, ud, bias, out_y, out_logdet, out_mask);
}

// Round 7
// 73.990 us; speedup vs baseline: 1.3260x; 1.3260x over previous
//
#include <hip/hip_runtime.h>

#define D 128
#define EPS 1e-3f

typedef short short8v __attribute__((ext_vector_type(8)));
typedef float f32x4  __attribute__((ext_vector_type(4)));
typedef unsigned short u16;
typedef u16 u16x4 __attribute__((ext_vector_type(4)));

// ws layout: [0,32K) U frags [wc(8)][s(4)][lane(64)]x8 bf16 ; [32K,64K) L frags ; [64K,+512) logdiag f32[128]
#define U_OFF 0
#define L_OFF (32*1024)
#define LD_OFF (64*1024)

__device__ __forceinline__ float softplus_f(float x) {
    return (x > 20.f) ? x : log1pf(expf(x));
}
__device__ __forceinline__ u16 f2bf(float f) {   // round-to-nearest-even f32->bf16
    unsigned u = __float_as_uint(f);
    unsigned r = (u + 0x7FFFu + ((u >> 16) & 1u)) >> 16;
    return (u16)r;
}

// Densify U^T / L^T into per-wave MFMA B-fragment order (bf16), + logdiag table.
// B-frag for 16x16x32: lane l holds B[k][col]: col = l&15, k = s*32 + (l>>4)*8 + e.
// B = U^T  =>  value = U[col][k]  (triangular-packed source, contiguous in k).
__global__ __launch_bounds__(256)
void lu_setup_kernel(const float* __restrict__ low_e,
                     const float* __restrict__ up_e,
                     const float* __restrict__ ud,
                     char* __restrict__ ws)
{
    const int wc = blockIdx.x;            // 0..7  col tile
    const int s  = threadIdx.x >> 6;      // 0..3  k step
    const int l  = threadIdx.x & 63;
    const int i  = wc * 16 + (l & 15);    // matrix row of U/L (= output col)
    const int k0 = s * 32 + (l >> 4) * 8;

    short8v uv8, lv8;
    #pragma unroll
    for (int e = 0; e < 8; ++e) {
        const int j = k0 + e;
        float uvf, lvf;
        if (j > i)      { uvf = up_e[i * 127 - (i * (i - 1)) / 2 + (j - i - 1)]; lvf = 0.f; }
        else if (j < i) { uvf = 0.f; lvf = low_e[(i * (i - 1)) / 2 + j]; }
        else            { uvf = softplus_f(ud[i]) + EPS; lvf = 1.f; }
        uv8[e] = (short)f2bf(uvf);
        lv8[e] = (short)f2bf(lvf);
    }
    const int fidx = (wc * 4 + s) * 64 + l;
    *((short8v*)(ws + U_OFF) + fidx) = uv8;
    *((short8v*)(ws + L_OFF) + fidx) = lv8;

    if (blockIdx.x == 0 && threadIdx.x < D) {
        const float dg = softplus_f(ud[threadIdx.x]) + EPS;
        ((float*)(ws + LD_OFF))[threadIdx.x] = logf(dg);
    }
}

// Main: per block 16 rows. GEMM1 Y1 = Xm*U^T ; mask ; GEMM2 Y2 = Y1m*L^T ; epilogue.
__global__ __launch_bounds__(512, 2)
void lu_mfma_kernel(const float* __restrict__ x,
                    const int*   __restrict__ mask,
                    const float* __restrict__ bias,
                    const char*  __restrict__ ws,
                    float* __restrict__ out_y,
                    float* __restrict__ out_logdet,
                    float* __restrict__ out_mask)
{
    __shared__ u16   xm_lds[16 * 128];   // swizzled bf16 A-tile; reused for Y1m
    __shared__ float x_lds[16 * 132];    // f32 x copy (padded stride vs bank conflicts)
    __shared__ u16   m_lds[16 * 132];    // mask flags

    const int t    = threadIdx.x;
    const int w    = t >> 6;             // wave 0..7 -> col tile
    const int l    = t & 63;
    const int row0 = blockIdx.x * 16;

    // ---- B-operand fragments from ws (coalesced 16B/lane, L2-hot) ----
    short8v ufrag[4], lfrag[4];
    #pragma unroll
    for (int s = 0; s < 4; ++s) {
        const int fidx = (w * 4 + s) * 64 + l;
        ufrag[s] = *((const short8v*)(ws + U_OFF) + fidx);
        lfrag[s] = *((const short8v*)(ws + L_OFF) + fidx);
    }

    // ---- stage x/mask (16 rows x 128), out_mask, logdet ----
    const int srow = t >> 5;             // 0..15
    const int c0   = (t & 31) * 4;
    const float4 xv = *(const float4*)(x    + (size_t)(row0 + srow) * D + c0);
    const int4   mv = *(const int4*)  (mask + (size_t)(row0 + srow) * D + c0);

    *(float4*)(out_mask + (size_t)(row0 + srow) * D + c0) =
        make_float4((float)mv.x, (float)mv.y, (float)mv.z, (float)mv.w);

    *(float4*)&x_lds[srow * 132 + c0] = xv;
    u16x4 mq; mq[0]=(u16)mv.x; mq[1]=(u16)mv.y; mq[2]=(u16)mv.z; mq[3]=(u16)mv.w;
    *(u16x4*)&m_lds[srow * 132 + c0] = mq;

    u16x4 xb;
    xb[0] = f2bf(mv.x ? xv.x : 0.f);
    xb[1] = f2bf(mv.y ? xv.y : 0.f);
    xb[2] = f2bf(mv.z ? xv.z : 0.f);
    xb[3] = f2bf(mv.w ? xv.w : 0.f);
    const int xi = (srow * 128 + c0) ^ ((srow & 7) << 3);
    *(u16x4*)&xm_lds[xi] = xb;

    const float4 ldg = *(const float4*)((const float*)(ws + LD_OFF) + c0);
    float part = (mv.x ? ldg.x : 0.f) + (mv.y ? ldg.y : 0.f) +
                 (mv.z ? ldg.z : 0.f) + (mv.w ? ldg.w : 0.f);
    #pragma unroll
    for (int sh = 16; sh > 0; sh >>= 1) part += __shfl_xor(part, sh, 64);
    if ((t & 31) == 0) out_logdet[row0 + srow] = part;

    __syncthreads();

    // ---- GEMM1: acc = Xm * U^T  (A: row=l&15, k=(l>>4)*8+e+32s) ----
    const int arow = l & 15;
    const int ablk = (l >> 4) * 8;
    f32x4 acc = {0.f, 0.f, 0.f, 0.f};
    #pragma unroll
    for (int s = 0; s < 4; ++s) {
        const int ai = (arow * 128 + s * 32 + ablk) ^ ((arow & 7) << 3);
        const short8v a = *(const short8v*)&xm_lds[ai];
        acc = __builtin_amdgcn_mfma_f32_16x16x32_bf16(a, ufrag[s], acc, 0, 0, 0);
    }

    __syncthreads();   // all A1 reads complete before overwrite

    // ---- mask C1, write Y1m (bf16, swizzled) back into xm_lds ----
    const int ccol = 16 * w + (l & 15);  // global feature index for this lane
    #pragma unroll
    for (int p = 0; p < 4; ++p) {
        const int r = (l >> 4) * 4 + p;
        const u16 m = m_lds[r * 132 + ccol];
        const float v = m ? acc[p] : 0.f;
        const int yi = (r * 128 + ccol) ^ ((r & 7) << 3);
        xm_lds[yi] = f2bf(v);
    }

    __syncthreads();

    // ---- GEMM2: acc2 = Y1m * L^T ----
    f32x4 acc2 = {0.f, 0.f, 0.f, 0.f};
    #pragma unroll
    for (int s = 0; s < 4; ++s) {
        const int ai = (arow * 128 + s * 32 + ablk) ^ ((arow & 7) << 3);
        const short8v a = *(const short8v*)&xm_lds[ai];
        acc2 = __builtin_amdgcn_mfma_f32_16x16x32_bf16(a, lfrag[s], acc2, 0, 0, 0);
    }

    // ---- epilogue: y = m ? (acc2 + bias) : x ----
    const float bv = bias[ccol];
    #pragma unroll
    for (int p = 0; p < 4; ++p) {
        const int r = (l >> 4) * 4 + p;
        const u16 m = m_lds[r * 132 + ccol];
        const float yv = m ? (acc2[p] + bv) : x_lds[r * 132 + ccol];
        out_y[(size_t)(row0 + r) * D + ccol] = yv;
    }
}

extern "C" void kernel_launch(void* const* d_in, const int* in_sizes, int n_in,
                              void* d_out, int out_size, void* d_ws, size_t ws_size,
                              hipStream_t stream) {
    const float* x     = (const float*)d_in[0];
    const int*   mask  = (const int*)d_in[1];
    const float* low_e = (const float*)d_in[2];
    const float* up_e  = (const float*)d_in[3];
    const float* ud    = (const float*)d_in[4];
    const float* bias  = (const float*)d_in[5];

    const int n_rows = in_sizes[0] / D;                // 8192
    float* out_y      = (float*)d_out;
    float* out_logdet = out_y + (size_t)n_rows * D;
    float* out_mask   = out_logdet + n_rows;

    char* ws = (char*)d_ws;

    lu_setup_kernel<<<8, 256, 0, stream>>>(low_e, up_e, ud, ws);
    lu_mfma_kernel<<<n_rows / 16, 512, 0, stream>>>(
        x, mask, bias, ws, out_y, out_logdet, out_mask);
}